// Round 1
// baseline (837.774 us; speedup 1.0000x reference)
//
#include <hip/hip_runtime.h>

#define NN 50000     // nodes
#define NE 800000    // edges
#define DD 64        // channels
#define NG 512       // graphs
#define NL 5         // layers

// ---------------- CSR build (by dst) ----------------

__global__ void count_deg_k(const int* __restrict__ dst, int* __restrict__ deg) {
    int e = blockIdx.x * blockDim.x + threadIdx.x;
    if (e < NE) atomicAdd(&deg[dst[e]], 1);
}

// start[i] = exclusive prefix of deg, allocated via one atomic per wave
// (row order in `col` is arbitrary but each node's range is contiguous —
//  all we need for aggregation).
__global__ void calc_start_k(const int* __restrict__ deg, int* __restrict__ start,
                             int* __restrict__ cursor) {
    int i = blockIdx.x * blockDim.x + threadIdx.x;
    int lane = threadIdx.x & 63;
    int d = (i < NN) ? deg[i] : 0;
    int incl = d;
#pragma unroll
    for (int off = 1; off < 64; off <<= 1) {
        int t = __shfl_up(incl, off, 64);
        if (lane >= off) incl += t;
    }
    int total = __shfl(incl, 63, 64);
    int base = 0;
    if (lane == 0 && total > 0) base = atomicAdd(cursor, total);
    base = __shfl(base, 0, 64);
    if (i < NN) start[i] = base + incl - d;
}

__global__ void fill_col_k(const int* __restrict__ src, const int* __restrict__ dst,
                           const int* __restrict__ start, int* __restrict__ fcnt,
                           int* __restrict__ col) {
    int e = blockIdx.x * blockDim.x + threadIdx.x;
    if (e < NE) {
        int d = dst[e];
        int p = atomicAdd(&fcnt[d], 1);
        col[start[d] + p] = src[e];
    }
}

// ---------------- per-layer kernels ----------------

// one wave per node, lane = channel: agg[i][c] = sum_{j in N(i)} h[col[j]][c]
__global__ void aggregate_k(const float* __restrict__ h, const int* __restrict__ start,
                            const int* __restrict__ deg, const int* __restrict__ col,
                            float* __restrict__ agg) {
    int w = (blockIdx.x * blockDim.x + threadIdx.x) >> 6;
    int lane = threadIdx.x & 63;
    if (w >= NN) return;
    int s = start[w], d = deg[w];
    float acc = 0.f;
    for (int j = 0; j < d; ++j) {
        int nb = col[s + j];
        acc += h[nb * DD + lane];
    }
    agg[w * DD + lane] = acc;
}

// out = relu([hin] + agg @ Wrel^T + b + hin @ Wroot^T)
// block = 256 threads = 4 nodes x 64 outputs; weights staged in LDS (pad 65)
template <int RESID>
__global__ void dense_layer_k(const float* __restrict__ agg, const float* __restrict__ hin,
                              const float* __restrict__ wrel, const float* __restrict__ brel,
                              const float* __restrict__ wroot, float* __restrict__ hout) {
    __shared__ float Wr[DD][DD + 1];
    __shared__ float Wo[DD][DD + 1];
    __shared__ float Ar[4][DD];
    __shared__ float Hr[4][DD];
    int t = threadIdx.x;
#pragma unroll
    for (int k = 0; k < 16; ++k) {
        int idx = t + k * 256;
        int o = idx >> 6, c = idx & 63;
        Wr[o][c] = wrel[idx];
        Wo[o][c] = wroot[idx];
    }
    int ni = t >> 6, o = t & 63;
    int node = blockIdx.x * 4 + ni;
    if (node < NN) {
        Ar[ni][o] = agg[node * DD + o];
        Hr[ni][o] = hin[node * DD + o];
    }
    __syncthreads();
    if (node >= NN) return;
    float acc = brel[o];
#pragma unroll
    for (int c = 0; c < DD; ++c) {
        acc += Ar[ni][c] * Wr[o][c] + Hr[ni][c] * Wo[o][c];
    }
    if (RESID) acc += Hr[ni][o];
    hout[node * DD + o] = fmaxf(acc, 0.f);
}

// ---------------- pooling (batch is sorted) ----------------

__global__ void pool_k(const float* __restrict__ h, const int* __restrict__ batch,
                       float* __restrict__ sums, int* __restrict__ cnt) {
    const int NP = 128;  // nodes per wave
    int w = (blockIdx.x * blockDim.x + threadIdx.x) >> 6;
    int lane = threadIdx.x & 63;
    int n0 = w * NP;
    if (n0 >= NN) return;
    int n1 = min(n0 + NP, NN);
    int g = batch[n0];
    float acc = 0.f;
    int run = 0;
    for (int i = n0; i < n1; ++i) {
        int gi = batch[i];
        if (gi != g) {
            atomicAdd(&sums[g * DD + lane], acc);
            if (lane == 0) atomicAdd(&cnt[g], run);
            acc = 0.f; run = 0; g = gi;
        }
        acc += h[i * DD + lane];
        run++;
    }
    atomicAdd(&sums[g * DD + lane], acc);
    if (lane == 0) atomicAdd(&cnt[g], run);
}

// ---------------- head: mean -> linear -> softmax ----------------

__global__ void head_k(const float* __restrict__ sums, const int* __restrict__ cnt,
                       const float* __restrict__ lin_w, const float* __restrict__ lin_b,
                       float* __restrict__ out) {
    int g = blockIdx.x * (blockDim.x >> 6) + (threadIdx.x >> 6);
    int o = threadIdx.x & 63;
    if (g >= NG) return;
    float c = (float)cnt[g];
    float inv = 1.0f / fmaxf(c, 1.0f);
    float acc = lin_b[o];
#pragma unroll 8
    for (int k = 0; k < DD; ++k) {
        acc += sums[g * DD + k] * inv * lin_w[o * DD + k];
    }
    float m = acc;
#pragma unroll
    for (int off = 32; off; off >>= 1) m = fmaxf(m, __shfl_xor(m, off, 64));
    float e = __expf(acc - m);
    float s = e;
#pragma unroll
    for (int off = 32; off; off >>= 1) s += __shfl_xor(s, off, 64);
    out[g * DD + o] = e / s;
}

// ---------------- driver ----------------

extern "C" void kernel_launch(void* const* d_in, const int* in_sizes, int n_in,
                              void* d_out, int out_size, void* d_ws, size_t ws_size,
                              hipStream_t stream) {
    const float* x      = (const float*)d_in[0];
    const int*   edge   = (const int*)d_in[1];   // [2, E]: src = edge, dst = edge+NE
    const int*   batch  = (const int*)d_in[2];
    const float* rel_w  = (const float*)d_in[3]; // [L, D, D]
    const float* rel_b  = (const float*)d_in[4]; // [L, D]
    const float* root_w = (const float*)d_in[5]; // [L, D, D]
    const float* lin_w  = (const float*)d_in[6]; // [D, D]
    const float* lin_b  = (const float*)d_in[7]; // [D]
    float* out = (float*)d_out;

    const int* src = edge;
    const int* dst = edge + NE;

    // workspace carve (all 256B aligned)
    char* p = (char*)d_ws;
    auto carve = [&](size_t bytes) {
        char* r = p;
        p += (bytes + 255) & ~(size_t)255;
        return (void*)r;
    };
    float* hA   = (float*)carve((size_t)NN * DD * 4);
    float* hB   = (float*)carve((size_t)NN * DD * 4);
    float* agg  = (float*)carve((size_t)NN * DD * 4);
    float* sums = (float*)carve((size_t)NG * DD * 4);
    int*   cnt  = (int*)carve((size_t)NG * 4);
    int*   deg  = (int*)carve((size_t)NN * 4);
    int*   strt = (int*)carve((size_t)NN * 4);
    int*   fcnt = (int*)carve((size_t)NN * 4);
    int*   col  = (int*)carve((size_t)NE * 4);
    int*   cur  = (int*)carve(4);

    // zero what we accumulate into (ws is poisoned 0xAA before every call)
    hipMemsetAsync(deg, 0, (size_t)NN * 4, stream);
    hipMemsetAsync(fcnt, 0, (size_t)NN * 4, stream);
    hipMemsetAsync(cur, 0, 4, stream);
    hipMemsetAsync(sums, 0, (size_t)NG * DD * 4, stream);
    hipMemsetAsync(cnt, 0, (size_t)NG * 4, stream);

    // CSR build
    count_deg_k<<<(NE + 255) / 256, 256, 0, stream>>>(dst, deg);
    calc_start_k<<<(NN + 255) / 256, 256, 0, stream>>>(deg, strt, cur);
    fill_col_k<<<(NE + 255) / 256, 256, 0, stream>>>(src, dst, strt, fcnt, col);

    const int nodeBlocks = (NN + 3) / 4;  // 4 nodes (waves) per 256-thread block

    // layer 0: x -> hA
    aggregate_k<<<nodeBlocks, 256, 0, stream>>>(x, strt, deg, col, agg);
    dense_layer_k<0><<<nodeBlocks, 256, 0, stream>>>(agg, x, rel_w, rel_b, root_w, hA);
    // layer 1: hA -> hB
    aggregate_k<<<nodeBlocks, 256, 0, stream>>>(hA, strt, deg, col, agg);
    dense_layer_k<0><<<nodeBlocks, 256, 0, stream>>>(agg, hA, rel_w + 4096, rel_b + 64,
                                                     root_w + 4096, hB);
    // layer 2: hB -> hA
    aggregate_k<<<nodeBlocks, 256, 0, stream>>>(hB, strt, deg, col, agg);
    dense_layer_k<0><<<nodeBlocks, 256, 0, stream>>>(agg, hB, rel_w + 2 * 4096, rel_b + 2 * 64,
                                                     root_w + 2 * 4096, hA);
    // layer 3 (residual): hA -> hB
    aggregate_k<<<nodeBlocks, 256, 0, stream>>>(hA, strt, deg, col, agg);
    dense_layer_k<1><<<nodeBlocks, 256, 0, stream>>>(agg, hA, rel_w + 3 * 4096, rel_b + 3 * 64,
                                                     root_w + 3 * 4096, hB);
    // layer 4 (residual): hB -> hA
    aggregate_k<<<nodeBlocks, 256, 0, stream>>>(hB, strt, deg, col, agg);
    dense_layer_k<1><<<nodeBlocks, 256, 0, stream>>>(agg, hB, rel_w + 4 * 4096, rel_b + 4 * 64,
                                                     root_w + 4 * 4096, hA);

    // pool + head
    const int wavesPool = (NN + 127) / 128;
    pool_k<<<(wavesPool + 3) / 4, 256, 0, stream>>>(hA, batch, sums, cnt);
    head_k<<<(NG + 3) / 4, 256, 0, stream>>>(sums, cnt, lin_w, lin_b, out);
}

// Round 2
// 586.350 us; speedup vs baseline: 1.4288x; 1.4288x over previous
//
#include <hip/hip_runtime.h>

#define NN 50000     // nodes
#define NE 800000    // edges
#define DD 64        // channels
#define NG 512       // graphs
#define NL 5         // layers

// ---------------- CSR build (by dst) ----------------

__global__ void count_deg_k(const int* __restrict__ dst, int* __restrict__ deg) {
    int e = blockIdx.x * blockDim.x + threadIdx.x;
    if (e < NE) atomicAdd(&deg[dst[e]], 1);
}

// start[i] = exclusive prefix of deg, allocated via one atomic per wave
__global__ void calc_start_k(const int* __restrict__ deg, int* __restrict__ start,
                             int* __restrict__ cursor) {
    int i = blockIdx.x * blockDim.x + threadIdx.x;
    int lane = threadIdx.x & 63;
    int d = (i < NN) ? deg[i] : 0;
    int incl = d;
#pragma unroll
    for (int off = 1; off < 64; off <<= 1) {
        int t = __shfl_up(incl, off, 64);
        if (lane >= off) incl += t;
    }
    int total = __shfl(incl, 63, 64);
    int base = 0;
    if (lane == 0 && total > 0) base = atomicAdd(cursor, total);
    base = __shfl(base, 0, 64);
    if (i < NN) start[i] = base + incl - d;
}

__global__ void fill_col_k(const int* __restrict__ src, const int* __restrict__ dst,
                           const int* __restrict__ start, int* __restrict__ fcnt,
                           int* __restrict__ col) {
    int e = blockIdx.x * blockDim.x + threadIdx.x;
    if (e < NE) {
        int d = dst[e];
        int p = atomicAdd(&fcnt[d], 1);
        col[start[d] + p] = src[e];
    }
}

// ---------------- aggregation ----------------
// one wave per node; lanes = 4 edge-groups x 16 channel-groups.
// Each lane loads float4 (16 B) of its edge's feature row -> 1 KB / instr,
// 4 independent edges in flight per iteration. Shuffle-reduce over edge
// groups at the end; lanes 0..15 write the 256 B result row as float4.
__global__ void aggregate_k(const float* __restrict__ h, const int* __restrict__ start,
                            const int* __restrict__ deg, const int* __restrict__ col,
                            float* __restrict__ agg) {
    int w = (blockIdx.x * blockDim.x + threadIdx.x) >> 6;
    int lane = threadIdx.x & 63;
    if (w >= NN) return;
    int eg = lane >> 4;   // edge group 0..3
    int cl = lane & 15;   // channel group: floats 4*cl .. 4*cl+3
    int s = start[w], d = deg[w];
    float4 acc = make_float4(0.f, 0.f, 0.f, 0.f);
    for (int j = eg; j < d; j += 4) {
        int nb = col[s + j];   // 4 consecutive dwords across the 4 groups
        float4 v = ((const float4*)(h + (size_t)nb * DD))[cl];
        acc.x += v.x; acc.y += v.y; acc.z += v.z; acc.w += v.w;
    }
#pragma unroll
    for (int off = 16; off <= 32; off <<= 1) {
        acc.x += __shfl_xor(acc.x, off, 64);
        acc.y += __shfl_xor(acc.y, off, 64);
        acc.z += __shfl_xor(acc.z, off, 64);
        acc.w += __shfl_xor(acc.w, off, 64);
    }
    if (eg == 0) {
        ((float4*)(agg + (size_t)w * DD))[cl] = acc;
    }
}

// ---------------- dense layer ----------------
// out = relu([hin] + agg @ Wrel^T + b + hin @ Wroot^T)
// block = 256 threads = 4 nodes x 64 outputs; weights staged in LDS (pad 65)
template <int RESID>
__global__ void dense_layer_k(const float* __restrict__ agg, const float* __restrict__ hin,
                              const float* __restrict__ wrel, const float* __restrict__ brel,
                              const float* __restrict__ wroot, float* __restrict__ hout) {
    __shared__ float Wr[DD][DD + 1];
    __shared__ float Wo[DD][DD + 1];
    __shared__ float Ar[4][DD];
    __shared__ float Hr[4][DD];
    int t = threadIdx.x;
#pragma unroll
    for (int k = 0; k < 16; ++k) {
        int idx = t + k * 256;
        int o = idx >> 6, c = idx & 63;
        Wr[o][c] = wrel[idx];
        Wo[o][c] = wroot[idx];
    }
    int ni = t >> 6, o = t & 63;
    int node = blockIdx.x * 4 + ni;
    if (node < NN) {
        Ar[ni][o] = agg[node * DD + o];
        Hr[ni][o] = hin[node * DD + o];
    }
    __syncthreads();
    if (node >= NN) return;
    float acc = brel[o];
#pragma unroll
    for (int c = 0; c < DD; ++c) {
        acc += Ar[ni][c] * Wr[o][c] + Hr[ni][c] * Wo[o][c];
    }
    if (RESID) acc += Hr[ni][o];
    hout[node * DD + o] = fmaxf(acc, 0.f);
}

// ---------------- pooling (batch is sorted) ----------------

__global__ void pool_k(const float* __restrict__ h, const int* __restrict__ batch,
                       float* __restrict__ sums, int* __restrict__ cnt) {
    const int NP = 32;  // nodes per wave (small -> enough waves to hide latency)
    int w = (blockIdx.x * blockDim.x + threadIdx.x) >> 6;
    int lane = threadIdx.x & 63;
    int n0 = w * NP;
    if (n0 >= NN) return;
    int n1 = min(n0 + NP, NN);
    int g = batch[n0];
    float acc = 0.f;
    int run = 0;
    for (int i = n0; i < n1; ++i) {
        int gi = batch[i];
        if (gi != g) {
            atomicAdd(&sums[g * DD + lane], acc);
            if (lane == 0) atomicAdd(&cnt[g], run);
            acc = 0.f; run = 0; g = gi;
        }
        acc += h[i * DD + lane];
        run++;
    }
    atomicAdd(&sums[g * DD + lane], acc);
    if (lane == 0) atomicAdd(&cnt[g], run);
}

// ---------------- head: mean -> linear -> softmax ----------------

__global__ void head_k(const float* __restrict__ sums, const int* __restrict__ cnt,
                       const float* __restrict__ lin_w, const float* __restrict__ lin_b,
                       float* __restrict__ out) {
    int g = blockIdx.x * (blockDim.x >> 6) + (threadIdx.x >> 6);
    int o = threadIdx.x & 63;
    if (g >= NG) return;
    float c = (float)cnt[g];
    float inv = 1.0f / fmaxf(c, 1.0f);
    float acc = lin_b[o];
#pragma unroll 8
    for (int k = 0; k < DD; ++k) {
        acc += sums[g * DD + k] * inv * lin_w[o * DD + k];
    }
    float m = acc;
#pragma unroll
    for (int off = 32; off; off >>= 1) m = fmaxf(m, __shfl_xor(m, off, 64));
    float e = __expf(acc - m);
    float s = e;
#pragma unroll
    for (int off = 32; off; off >>= 1) s += __shfl_xor(s, off, 64);
    out[g * DD + o] = e / s;
}

// ---------------- driver ----------------

extern "C" void kernel_launch(void* const* d_in, const int* in_sizes, int n_in,
                              void* d_out, int out_size, void* d_ws, size_t ws_size,
                              hipStream_t stream) {
    const float* x      = (const float*)d_in[0];
    const int*   edge   = (const int*)d_in[1];   // [2, E]: src = edge, dst = edge+NE
    const int*   batch  = (const int*)d_in[2];
    const float* rel_w  = (const float*)d_in[3]; // [L, D, D]
    const float* rel_b  = (const float*)d_in[4]; // [L, D]
    const float* root_w = (const float*)d_in[5]; // [L, D, D]
    const float* lin_w  = (const float*)d_in[6]; // [D, D]
    const float* lin_b  = (const float*)d_in[7]; // [D]
    float* out = (float*)d_out;

    const int* src = edge;
    const int* dst = edge + NE;

    // workspace carve (all 256B aligned)
    char* p = (char*)d_ws;
    auto carve = [&](size_t bytes) {
        char* r = p;
        p += (bytes + 255) & ~(size_t)255;
        return (void*)r;
    };
    float* hA   = (float*)carve((size_t)NN * DD * 4);
    float* hB   = (float*)carve((size_t)NN * DD * 4);
    float* agg  = (float*)carve((size_t)NN * DD * 4);
    int*   col  = (int*)carve((size_t)NE * 4);
    int*   strt = (int*)carve((size_t)NN * 4);
    // ---- contiguous zero region (single memset) ----
    char* zbase = p;
    float* sums = (float*)carve((size_t)NG * DD * 4);
    int*   cnt  = (int*)carve((size_t)NG * 4);
    int*   deg  = (int*)carve((size_t)NN * 4);
    int*   fcnt = (int*)carve((size_t)NN * 4);
    int*   cur  = (int*)carve(4);
    size_t zbytes = (size_t)(p - zbase);

    hipMemsetAsync(zbase, 0, zbytes, stream);

    // CSR build
    count_deg_k<<<(NE + 255) / 256, 256, 0, stream>>>(dst, deg);
    calc_start_k<<<(NN + 255) / 256, 256, 0, stream>>>(deg, strt, cur);
    fill_col_k<<<(NE + 255) / 256, 256, 0, stream>>>(src, dst, strt, fcnt, col);

    const int nodeBlocks = (NN + 3) / 4;  // 4 nodes (waves) per 256-thread block

    // layer 0: x -> hA
    aggregate_k<<<nodeBlocks, 256, 0, stream>>>(x, strt, deg, col, agg);
    dense_layer_k<0><<<nodeBlocks, 256, 0, stream>>>(agg, x, rel_w, rel_b, root_w, hA);
    // layer 1: hA -> hB
    aggregate_k<<<nodeBlocks, 256, 0, stream>>>(hA, strt, deg, col, agg);
    dense_layer_k<0><<<nodeBlocks, 256, 0, stream>>>(agg, hA, rel_w + 4096, rel_b + 64,
                                                     root_w + 4096, hB);
    // layer 2: hB -> hA
    aggregate_k<<<nodeBlocks, 256, 0, stream>>>(hB, strt, deg, col, agg);
    dense_layer_k<0><<<nodeBlocks, 256, 0, stream>>>(agg, hB, rel_w + 2 * 4096, rel_b + 2 * 64,
                                                     root_w + 2 * 4096, hA);
    // layer 3 (residual): hA -> hB
    aggregate_k<<<nodeBlocks, 256, 0, stream>>>(hA, strt, deg, col, agg);
    dense_layer_k<1><<<nodeBlocks, 256, 0, stream>>>(agg, hA, rel_w + 3 * 4096, rel_b + 3 * 64,
                                                     root_w + 3 * 4096, hB);
    // layer 4 (residual): hB -> hA
    aggregate_k<<<nodeBlocks, 256, 0, stream>>>(hB, strt, deg, col, agg);
    dense_layer_k<1><<<nodeBlocks, 256, 0, stream>>>(agg, hB, rel_w + 4 * 4096, rel_b + 4 * 64,
                                                     root_w + 4 * 4096, hA);

    // pool + head
    const int wavesPool = (NN + 31) / 32;
    pool_k<<<(wavesPool + 3) / 4, 256, 0, stream>>>(hA, batch, sums, cnt);
    head_k<<<(NG + 3) / 4, 256, 0, stream>>>(sums, cnt, lin_w, lin_b, out);
}

// Round 3
// 547.978 us; speedup vs baseline: 1.5288x; 1.0700x over previous
//
#include <hip/hip_runtime.h>

#define NN 50000     // nodes
#define NE 800000    // edges
#define DD 64        // channels
#define NG 512       // graphs
#define NL 5         // layers

// ---------------- CSR build (by dst) ----------------

__global__ void count_deg_k(const int* __restrict__ dst, int* __restrict__ deg) {
    int e = blockIdx.x * blockDim.x + threadIdx.x;
    if (e < NE) atomicAdd(&deg[dst[e]], 1);
}

// start[i] = exclusive prefix of deg, allocated via one atomic per wave
__global__ void calc_start_k(const int* __restrict__ deg, int* __restrict__ start,
                             int* __restrict__ cursor) {
    int i = blockIdx.x * blockDim.x + threadIdx.x;
    int lane = threadIdx.x & 63;
    int d = (i < NN) ? deg[i] : 0;
    int incl = d;
#pragma unroll
    for (int off = 1; off < 64; off <<= 1) {
        int t = __shfl_up(incl, off, 64);
        if (lane >= off) incl += t;
    }
    int total = __shfl(incl, 63, 64);
    int base = 0;
    if (lane == 0 && total > 0) base = atomicAdd(cursor, total);
    base = __shfl(base, 0, 64);
    if (i < NN) start[i] = base + incl - d;
}

__global__ void fill_col_k(const int* __restrict__ src, const int* __restrict__ dst,
                           const int* __restrict__ start, int* __restrict__ fcnt,
                           int* __restrict__ col) {
    int e = blockIdx.x * blockDim.x + threadIdx.x;
    if (e < NE) {
        int d = dst[e];
        int p = atomicAdd(&fcnt[d], 1);
        col[start[d] + p] = src[e];
    }
}

// ---------------- aggregation ----------------
// one wave per node; lanes = 4 edge-groups x 16 channel-groups.
__global__ void aggregate_k(const float* __restrict__ h, const int* __restrict__ start,
                            const int* __restrict__ deg, const int* __restrict__ col,
                            float* __restrict__ agg) {
    int w = (blockIdx.x * blockDim.x + threadIdx.x) >> 6;
    int lane = threadIdx.x & 63;
    if (w >= NN) return;
    int eg = lane >> 4;   // edge group 0..3
    int cl = lane & 15;   // channel group: floats 4*cl .. 4*cl+3
    int s = start[w], d = deg[w];
    float4 acc = make_float4(0.f, 0.f, 0.f, 0.f);
    for (int j = eg; j < d; j += 4) {
        int nb = col[s + j];
        float4 v = ((const float4*)(h + (size_t)nb * DD))[cl];
        acc.x += v.x; acc.y += v.y; acc.z += v.z; acc.w += v.w;
    }
#pragma unroll
    for (int off = 16; off <= 32; off <<= 1) {
        acc.x += __shfl_xor(acc.x, off, 64);
        acc.y += __shfl_xor(acc.y, off, 64);
        acc.z += __shfl_xor(acc.z, off, 64);
        acc.w += __shfl_xor(acc.w, off, 64);
    }
    if (eg == 0) {
        ((float4*)(agg + (size_t)w * DD))[cl] = acc;
    }
}

// ---------------- dense layer v2 ----------------
// out = relu([hin] + agg @ Wrel^T + b + hin @ Wroot^T)
// block = 256 threads, 64 nodes/block. Weights in LDS (XOR-swizzled, b128
// conflict-free); activations read from global as float4 broadcasts (L1-hot).
// Thread (oq = t&15, nq = t>>4) computes acc[4 nodes][4 outputs].
template <int RESID>
__global__ void dense_layer_k(const float* __restrict__ agg, const float* __restrict__ hin,
                              const float* __restrict__ wrel, const float* __restrict__ brel,
                              const float* __restrict__ wroot, float* __restrict__ hout) {
    __shared__ float4 Wr4[DD][16];   // [o][swizzled c-quad]
    __shared__ float4 Wo4[DD][16];
    int t = threadIdx.x;
    const float4* wrel4  = (const float4*)wrel;
    const float4* wroot4 = (const float4*)wroot;
#pragma unroll
    for (int k = 0; k < 4; ++k) {
        int idx = t + k * 256;           // float4 slot 0..1023 = o*16 + cq
        int o = idx >> 4, cq = idx & 15;
        int p = cq ^ ((o >> 2) & 7);     // swizzle: spreads oq-broadcast reads
        Wr4[o][p] = wrel4[idx];
        Wo4[o][p] = wroot4[idx];
    }
    __syncthreads();

    int oq = t & 15;        // output quad: o = 4*oq + j
    int nq = t >> 4;        // node quad within tile: n = tile + 4*nq + i
    int tile = blockIdx.x * 64;
    int swz = oq & 7;       // (row>>2)&7 for rows 4*oq+j is just oq&7

    // clamped node rows (guard against reading past input allocations)
    int nrow[4];
#pragma unroll
    for (int i = 0; i < 4; ++i) {
        int n = tile + 4 * nq + i;
        nrow[i] = (n < NN) ? n : 0;
    }

    float acc[4][4];
#pragma unroll
    for (int i = 0; i < 4; ++i)
#pragma unroll
        for (int j = 0; j < 4; ++j) acc[i][j] = 0.f;

    const float4* agg4 = (const float4*)agg;
    const float4* hin4 = (const float4*)hin;

#pragma unroll 4
    for (int cq = 0; cq < 16; ++cq) {
        float4 wr[4], wo[4];
        int p = cq ^ swz;
#pragma unroll
        for (int j = 0; j < 4; ++j) {
            wr[j] = Wr4[4 * oq + j][p];
            wo[j] = Wo4[4 * oq + j][p];
        }
#pragma unroll
        for (int i = 0; i < 4; ++i) {
            float4 a = agg4[(size_t)nrow[i] * 16 + cq];
            float4 h = hin4[(size_t)nrow[i] * 16 + cq];
#pragma unroll
            for (int j = 0; j < 4; ++j) {
                acc[i][j] += a.x * wr[j].x + a.y * wr[j].y + a.z * wr[j].z + a.w * wr[j].w
                           + h.x * wo[j].x + h.y * wo[j].y + h.z * wo[j].z + h.w * wo[j].w;
            }
        }
    }

    float4 bias = ((const float4*)brel)[oq];
#pragma unroll
    for (int i = 0; i < 4; ++i) {
        int n = tile + 4 * nq + i;
        if (n >= NN) break;
        float4 r;
        r.x = acc[i][0] + bias.x;
        r.y = acc[i][1] + bias.y;
        r.z = acc[i][2] + bias.z;
        r.w = acc[i][3] + bias.w;
        if (RESID) {
            float4 hr = hin4[(size_t)n * 16 + oq];
            r.x += hr.x; r.y += hr.y; r.z += hr.z; r.w += hr.w;
        }
        r.x = fmaxf(r.x, 0.f); r.y = fmaxf(r.y, 0.f);
        r.z = fmaxf(r.z, 0.f); r.w = fmaxf(r.w, 0.f);
        ((float4*)hout)[(size_t)n * 16 + oq] = r;
    }
}

// ---------------- pooling (batch is sorted) ----------------

__global__ void pool_k(const float* __restrict__ h, const int* __restrict__ batch,
                       float* __restrict__ sums, int* __restrict__ cnt) {
    const int NP = 32;  // nodes per wave
    int w = (blockIdx.x * blockDim.x + threadIdx.x) >> 6;
    int lane = threadIdx.x & 63;
    int n0 = w * NP;
    if (n0 >= NN) return;
    int n1 = min(n0 + NP, NN);
    int g = batch[n0];
    float acc = 0.f;
    int run = 0;
    for (int i = n0; i < n1; ++i) {
        int gi = batch[i];
        if (gi != g) {
            atomicAdd(&sums[g * DD + lane], acc);
            if (lane == 0) atomicAdd(&cnt[g], run);
            acc = 0.f; run = 0; g = gi;
        }
        acc += h[i * DD + lane];
        run++;
    }
    atomicAdd(&sums[g * DD + lane], acc);
    if (lane == 0) atomicAdd(&cnt[g], run);
}

// ---------------- head: mean -> linear -> softmax ----------------

__global__ void head_k(const float* __restrict__ sums, const int* __restrict__ cnt,
                       const float* __restrict__ lin_w, const float* __restrict__ lin_b,
                       float* __restrict__ out) {
    int g = blockIdx.x * (blockDim.x >> 6) + (threadIdx.x >> 6);
    int o = threadIdx.x & 63;
    if (g >= NG) return;
    float c = (float)cnt[g];
    float inv = 1.0f / fmaxf(c, 1.0f);
    float acc = lin_b[o];
#pragma unroll 8
    for (int k = 0; k < DD; ++k) {
        acc += sums[g * DD + k] * inv * lin_w[o * DD + k];
    }
    float m = acc;
#pragma unroll
    for (int off = 32; off; off >>= 1) m = fmaxf(m, __shfl_xor(m, off, 64));
    float e = __expf(acc - m);
    float s = e;
#pragma unroll
    for (int off = 32; off; off >>= 1) s += __shfl_xor(s, off, 64);
    out[g * DD + o] = e / s;
}

// ---------------- driver ----------------

extern "C" void kernel_launch(void* const* d_in, const int* in_sizes, int n_in,
                              void* d_out, int out_size, void* d_ws, size_t ws_size,
                              hipStream_t stream) {
    const float* x      = (const float*)d_in[0];
    const int*   edge   = (const int*)d_in[1];   // [2, E]: src = edge, dst = edge+NE
    const int*   batch  = (const int*)d_in[2];
    const float* rel_w  = (const float*)d_in[3]; // [L, D, D]
    const float* rel_b  = (const float*)d_in[4]; // [L, D]
    const float* root_w = (const float*)d_in[5]; // [L, D, D]
    const float* lin_w  = (const float*)d_in[6]; // [D, D]
    const float* lin_b  = (const float*)d_in[7]; // [D]
    float* out = (float*)d_out;

    const int* src = edge;
    const int* dst = edge + NE;

    // workspace carve (all 256B aligned)
    char* p = (char*)d_ws;
    auto carve = [&](size_t bytes) {
        char* r = p;
        p += (bytes + 255) & ~(size_t)255;
        return (void*)r;
    };
    float* hA   = (float*)carve((size_t)NN * DD * 4);
    float* hB   = (float*)carve((size_t)NN * DD * 4);
    float* agg  = (float*)carve((size_t)NN * DD * 4);
    int*   col  = (int*)carve((size_t)NE * 4);
    int*   strt = (int*)carve((size_t)NN * 4);
    // ---- contiguous zero region (single memset) ----
    char* zbase = p;
    float* sums = (float*)carve((size_t)NG * DD * 4);
    int*   cnt  = (int*)carve((size_t)NG * 4);
    int*   deg  = (int*)carve((size_t)NN * 4);
    int*   fcnt = (int*)carve((size_t)NN * 4);
    int*   cur  = (int*)carve(4);
    size_t zbytes = (size_t)(p - zbase);

    hipMemsetAsync(zbase, 0, zbytes, stream);

    // CSR build
    count_deg_k<<<(NE + 255) / 256, 256, 0, stream>>>(dst, deg);
    calc_start_k<<<(NN + 255) / 256, 256, 0, stream>>>(deg, strt, cur);
    fill_col_k<<<(NE + 255) / 256, 256, 0, stream>>>(src, dst, strt, fcnt, col);

    const int aggBlocks = (NN + 3) / 4;     // 4 waves (nodes) per block
    const int dnsBlocks = (NN + 63) / 64;   // 64 nodes per block

    // layer 0: x -> hA
    aggregate_k<<<aggBlocks, 256, 0, stream>>>(x, strt, deg, col, agg);
    dense_layer_k<0><<<dnsBlocks, 256, 0, stream>>>(agg, x, rel_w, rel_b, root_w, hA);
    // layer 1: hA -> hB
    aggregate_k<<<aggBlocks, 256, 0, stream>>>(hA, strt, deg, col, agg);
    dense_layer_k<0><<<dnsBlocks, 256, 0, stream>>>(agg, hA, rel_w + 4096, rel_b + 64,
                                                    root_w + 4096, hB);
    // layer 2: hB -> hA
    aggregate_k<<<aggBlocks, 256, 0, stream>>>(hB, strt, deg, col, agg);
    dense_layer_k<0><<<dnsBlocks, 256, 0, stream>>>(agg, hB, rel_w + 2 * 4096, rel_b + 2 * 64,
                                                    root_w + 2 * 4096, hA);
    // layer 3 (residual): hA -> hB
    aggregate_k<<<aggBlocks, 256, 0, stream>>>(hA, strt, deg, col, agg);
    dense_layer_k<1><<<dnsBlocks, 256, 0, stream>>>(agg, hA, rel_w + 3 * 4096, rel_b + 3 * 64,
                                                    root_w + 3 * 4096, hB);
    // layer 4 (residual): hB -> hA
    aggregate_k<<<aggBlocks, 256, 0, stream>>>(hB, strt, deg, col, agg);
    dense_layer_k<1><<<dnsBlocks, 256, 0, stream>>>(agg, hB, rel_w + 4 * 4096, rel_b + 4 * 64,
                                                    root_w + 4 * 4096, hA);

    // pool + head
    const int wavesPool = (NN + 31) / 32;
    pool_k<<<(wavesPool + 3) / 4, 256, 0, stream>>>(hA, batch, sums, cnt);
    head_k<<<(NG + 3) / 4, 256, 0, stream>>>(sums, cnt, lin_w, lin_b, out);
}